// Round 3
// 349.285 us; speedup vs baseline: 1.0809x; 1.0809x over previous
//
#include <hip/hip_runtime.h>

#define H 16
#define D 24
#define DS 384
#define CZ 128
#define S 512
#define EPSV 1e-5f

// ================= Kernel 1: tiled Q/K/VT/G projections (baseline, passing) =================
__global__ __launch_bounds__(256) void proj_kernel(
    const float* __restrict__ s, const float* __restrict__ q_w, const float* __restrict__ q_b,
    const float* __restrict__ k_w, const float* __restrict__ v_w, const float* __restrict__ g_w,
    float* __restrict__ Q, float* __restrict__ K, float* __restrict__ VT, float* __restrict__ G)
{
    const int b = blockIdx.x;
    const int mat = b / 48;          // 0:Q 1:K 2:V 3:G
    const int t = b % 48;
    const int by = t / 6, bx = t % 6;
    const float* w = (mat == 0) ? q_w : (mat == 1) ? k_w : (mat == 2) ? v_w : g_w;

    __shared__ float As[32][68];
    __shared__ float Ws[32][68];

    const int tid = threadIdx.x;
    const int tx = tid & 15, ty = tid >> 4;
    const int r8 = tid >> 3;
    const int c4 = tid & 7;

    float acc[4][4] = {};
    for (int kc = 0; kc < DS; kc += 32) {
        __syncthreads();
#pragma unroll
        for (int pass = 0; pass < 2; ++pass) {
            int r = r8 + pass * 32;
            float4 sv = *(const float4*)(s + (by * 64 + r) * DS + kc + c4 * 4);
            float4 wv = *(const float4*)(w + (bx * 64 + r) * DS + kc + c4 * 4);
            As[c4 * 4 + 0][r] = sv.x; As[c4 * 4 + 1][r] = sv.y;
            As[c4 * 4 + 2][r] = sv.z; As[c4 * 4 + 3][r] = sv.w;
            Ws[c4 * 4 + 0][r] = wv.x; Ws[c4 * 4 + 1][r] = wv.y;
            Ws[c4 * 4 + 2][r] = wv.z; Ws[c4 * 4 + 3][r] = wv.w;
        }
        __syncthreads();
#pragma unroll
        for (int k = 0; k < 32; ++k) {
            float4 a4 = *(const float4*)&As[k][ty * 4];
            float4 b4 = *(const float4*)&Ws[k][tx * 4];
            acc[0][0] += a4.x * b4.x; acc[0][1] += a4.x * b4.y; acc[0][2] += a4.x * b4.z; acc[0][3] += a4.x * b4.w;
            acc[1][0] += a4.y * b4.x; acc[1][1] += a4.y * b4.y; acc[1][2] += a4.y * b4.z; acc[1][3] += a4.y * b4.w;
            acc[2][0] += a4.z * b4.x; acc[2][1] += a4.z * b4.y; acc[2][2] += a4.z * b4.z; acc[2][3] += a4.z * b4.w;
            acc[3][0] += a4.w * b4.x; acc[3][1] += a4.w * b4.y; acc[3][2] += a4.w * b4.z; acc[3][3] += a4.w * b4.w;
        }
    }

    const int r0 = by * 64 + ty * 4;
    const int c0 = bx * 64 + tx * 4;
    if (mat == 2) {
#pragma unroll
        for (int ii = 0; ii < 4; ++ii)
#pragma unroll
            for (int jj = 0; jj < 4; ++jj)
                VT[(c0 + jj) * S + (r0 + ii)] = acc[ii][jj];
    } else {
        float* dst = (mat == 0) ? Q : (mat == 1) ? K : G;
#pragma unroll
        for (int ii = 0; ii < 4; ++ii) {
            float4 v;
            v.x = acc[ii][0]; v.y = acc[ii][1]; v.z = acc[ii][2]; v.w = acc[ii][3];
            if (mat == 0) {
                v.x += q_b[c0 + 0]; v.y += q_b[c0 + 1]; v.z += q_b[c0 + 2]; v.w += q_b[c0 + 3];
            } else if (mat == 3) {
                v.x = 1.f / (1.f + __expf(-v.x)); v.y = 1.f / (1.f + __expf(-v.y));
                v.z = 1.f / (1.f + __expf(-v.z)); v.w = 1.f / (1.f + __expf(-v.w));
            }
            *(float4*)(dst + (r0 + ii) * DS + c0) = v;
        }
    }
}

// ================= Kernel 2a: register-z + broadcast-a LN/bias/QK scores =================
// grid 4096: b = q*8 + jt, 64 key-rows per block.
// Phase 1: wave w owns channel slice [32w,32w+32); lane = key row. z loaded global->regs
//   (one 128B line per row per wave, fully consumed). a_s read with WAVE-UNIFORM addresses
//   (same-address broadcast => zero bank conflicts). fp32 throughout.
// Phase 2: thread (row=t>>2, head-quad=t&3) combines 4 wave-partials, adds QK + LN affine.
__global__ __launch_bounds__(256) void score_kernel(
    const float* __restrict__ z, const float* __restrict__ seq_mask,
    const float* __restrict__ z_ln_w, const float* __restrict__ z_ln_b,
    const float* __restrict__ z_w,
    const float* __restrict__ Q, const float* __restrict__ K,
    float* __restrict__ scores)
{
    const int b = blockIdx.x;
    const int q = b >> 3;
    const int j0 = (b & 7) * 64;
    const int tid = threadIdx.x;
    const int w = tid >> 6;        // wave id -> channel slice
    const int lane = tid & 63;     // key row within tile

    __shared__ float a_s[H][CZ + 4];      // folded lnw*zw        8.4 KB
    __shared__ float AhBh[2][H];          //                      128 B
    __shared__ float qrow[DS];            //                      1.5 KB
    __shared__ float stats[4][2][68];     // [wave][sum/sq][row]  2.2 KB
    __shared__ float opart[4][H][68];     // [wave][head][row]    17.4 KB
    __shared__ float buf[H][68];          // output transpose     4.3 KB

    // ---- Phase 0: stage a_s (+Ah/Bh) and qrow ----
    {
        const int h = tid >> 4;           // 0..15
        const int c8 = (tid & 15) * 8;    // 8 channels each
        float A = 0.f, Bv = 0.f;
#pragma unroll
        for (int p = 0; p < 2; ++p) {
            float4 wz = *(const float4*)(z_w + h * CZ + c8 + p * 4);
            float4 lw = *(const float4*)(z_ln_w + c8 + p * 4);
            float4 lb = *(const float4*)(z_ln_b + c8 + p * 4);
            float4 a;
            a.x = lw.x * wz.x; a.y = lw.y * wz.y; a.z = lw.z * wz.z; a.w = lw.w * wz.w;
            *(float4*)&a_s[h][c8 + p * 4] = a;
            A += a.x + a.y + a.z + a.w;
            Bv += lb.x * wz.x + lb.y * wz.y + lb.z * wz.z + lb.w * wz.w;
        }
#pragma unroll
        for (int m = 1; m < 16; m <<= 1) {
            A += __shfl_xor(A, m);
            Bv += __shfl_xor(Bv, m);
        }
        if ((tid & 15) == 0) { AhBh[0][h] = A; AhBh[1][h] = Bv; }
    }
    for (int i = tid; i < DS; i += 256) qrow[i] = Q[q * DS + i];
    __syncthreads();

    // ---- Phase 1: per-wave partial GEMM over its 32-channel slice ----
    {
        const int c0 = w * 32;
        const float* zr = z + ((long)q * S + j0 + lane) * CZ + c0;
        float4 zf[8];
#pragma unroll
        for (int t = 0; t < 8; ++t) zf[t] = *(const float4*)(zr + t * 4);

        float s1 = 0.f, s2 = 0.f;
#pragma unroll
        for (int t = 0; t < 8; ++t) {
            s1 += zf[t].x + zf[t].y + zf[t].z + zf[t].w;
            s2 += zf[t].x * zf[t].x + zf[t].y * zf[t].y + zf[t].z * zf[t].z + zf[t].w * zf[t].w;
        }
        stats[w][0][lane] = s1;
        stats[w][1][lane] = s2;

#pragma unroll
        for (int h = 0; h < H; ++h) {
            float acc = 0.f;
#pragma unroll
            for (int t = 0; t < 8; ++t) {
                float4 a4 = *(const float4*)&a_s[h][c0 + t * 4];   // wave-uniform: broadcast
                acc += zf[t].x * a4.x + zf[t].y * a4.y + zf[t].z * a4.z + zf[t].w * a4.w;
            }
            opart[w][h][lane] = acc;
        }
    }
    __syncthreads();

    // ---- Phase 2: combine partials, LN affine + QK, write via transpose buffer ----
    {
        const int r = tid >> 2;           // key row 0..63
        const int hq = tid & 3;           // head quad
        float s1 = stats[0][0][r] + stats[1][0][r] + stats[2][0][r] + stats[3][0][r];
        float s2 = stats[0][1][r] + stats[1][1][r] + stats[2][1][r] + stats[3][1][r];
        const float mu = s1 * (1.f / 128.f);
        const float rs = rsqrtf(s2 * (1.f / 128.f) - mu * mu + EPSV);
        const float mk = seq_mask[j0 + r];
        const float scale = 0.2041241452319315f;  // 1/sqrt(24)
        const float* krow = K + (long)(j0 + r) * DS;

#pragma unroll
        for (int i = 0; i < 4; ++i) {
            const int h = hq * 4 + i;
            float dza = opart[0][h][r] + opart[1][h][r] + opart[2][h][r] + opart[3][h][r];
            const float4* k4 = (const float4*)(krow + h * D);
            const float4* q4 = (const float4*)(qrow + h * D);
            float qk = 0.f;
#pragma unroll
            for (int t = 0; t < 6; ++t) {
                float4 kv = k4[t];
                float4 qv = q4[t];
                qk += kv.x * qv.x + kv.y * qv.y + kv.z * qv.z + kv.w * qv.w;
            }
            const float bias = rs * dza - mu * rs * AhBh[0][h] + AhBh[1][h];
            buf[h][r] = qk * scale + bias + mk;
        }
    }
    __syncthreads();

    // coalesced store: 16 threads per head, float4 along j
    {
        const int h = tid >> 4, j4 = tid & 15;
        float4 v = *(const float4*)&buf[h][j4 * 4];
        *(float4*)(scores + ((q << 4) + h) * S + j0 + j4 * 4) = v;
    }
}

// ================= Kernel 2b: softmax + PV + gate (baseline, passing) =================
__global__ __launch_bounds__(256) void spv_kernel(
    const float* __restrict__ scores, const float* __restrict__ VT,
    const float* __restrict__ G, float* __restrict__ og)
{
    const int q = blockIdx.x;
    const int tid = threadIdx.x;
    const int wv = tid >> 6;
    const int lane = tid & 63;

    __shared__ float sc[H][S + 4];
    __shared__ float opart[4][DS];
    __shared__ float inv_l[H];

    for (int i = tid; i < H * (S / 4); i += 256) {
        int row = i >> 7, f4 = i & 127;
        float4 v = ((const float4*)(scores + ((q << 4) + row) * S))[f4];
        *(float4*)&sc[row][f4 * 4] = v;
    }
    __syncthreads();

#pragma unroll
    for (int i = 0; i < 4; ++i) {
        int h = wv * 4 + i;
        float m = -1e30f;
        for (int j = lane; j < S; j += 64) m = fmaxf(m, sc[h][j]);
#pragma unroll
        for (int mk = 1; mk < 64; mk <<= 1) m = fmaxf(m, __shfl_xor(m, mk));
        float sum = 0.f;
        for (int j = lane; j < S; j += 64) {
            float p = __expf(sc[h][j] - m);
            sc[h][j] = p;
            sum += p;
        }
#pragma unroll
        for (int mk = 1; mk < 64; mk <<= 1) sum += __shfl_xor(sum, mk);
        if (lane == 0) inv_l[h] = 1.f / sum;
    }
    __syncthreads();

#pragma unroll
    for (int ii = 0; ii < 6; ++ii) {
        int idx = ii * 64 + lane;
        int h = idx / 24;
        float acc = 0.f;
        const float4* vt4 = (const float4*)(VT + idx * S + wv * 128);
        const float4* sc4 = (const float4*)&sc[h][wv * 128];
#pragma unroll
        for (int t = 0; t < 32; ++t) {
            float4 p = sc4[t];
            float4 v = vt4[t];
            acc += p.x * v.x + p.y * v.y + p.z * v.z + p.w * v.w;
        }
        opart[wv][idx] = acc;
    }
    __syncthreads();
    for (int i = tid; i < DS; i += 256) {
        float o = opart[0][i] + opart[1][i] + opart[2][i] + opart[3][i];
        int h = i / 24;
        og[q * DS + i] = o * inv_l[h] * G[q * DS + i];
    }
}

// ================= Kernel 3: tiled output projection (baseline, passing) =================
__global__ __launch_bounds__(256) void out_kernel(
    const float* __restrict__ og, const float* __restrict__ o_w, float* __restrict__ out)
{
    const int b = blockIdx.x;
    const int by = b / 6, bx = b % 6;

    __shared__ float As[32][68];
    __shared__ float Ws[32][68];

    const int tid = threadIdx.x;
    const int tx = tid & 15, ty = tid >> 4;
    const int r8 = tid >> 3;
    const int c4 = tid & 7;

    float acc[4][4] = {};
    for (int kc = 0; kc < DS; kc += 32) {
        __syncthreads();
#pragma unroll
        for (int pass = 0; pass < 2; ++pass) {
            int r = r8 + pass * 32;
            float4 sv = *(const float4*)(og + (by * 64 + r) * DS + kc + c4 * 4);
            float4 wvv = *(const float4*)(o_w + (bx * 64 + r) * DS + kc + c4 * 4);
            As[c4 * 4 + 0][r] = sv.x; As[c4 * 4 + 1][r] = sv.y;
            As[c4 * 4 + 2][r] = sv.z; As[c4 * 4 + 3][r] = sv.w;
            Ws[c4 * 4 + 0][r] = wvv.x; Ws[c4 * 4 + 1][r] = wvv.y;
            Ws[c4 * 4 + 2][r] = wvv.z; Ws[c4 * 4 + 3][r] = wvv.w;
        }
        __syncthreads();
#pragma unroll
        for (int k = 0; k < 32; ++k) {
            float4 a4 = *(const float4*)&As[k][ty * 4];
            float4 b4 = *(const float4*)&Ws[k][tx * 4];
            acc[0][0] += a4.x * b4.x; acc[0][1] += a4.x * b4.y; acc[0][2] += a4.x * b4.z; acc[0][3] += a4.x * b4.w;
            acc[1][0] += a4.y * b4.x; acc[1][1] += a4.y * b4.y; acc[1][2] += a4.y * b4.z; acc[1][3] += a4.y * b4.w;
            acc[2][0] += a4.z * b4.x; acc[2][1] += a4.z * b4.y; acc[2][2] += a4.z * b4.z; acc[2][3] += a4.z * b4.w;
            acc[3][0] += a4.w * b4.x; acc[3][1] += a4.w * b4.y; acc[3][2] += a4.w * b4.z; acc[3][3] += a4.w * b4.w;
        }
    }

    const int r0 = by * 64 + ty * 4;
    const int c0 = bx * 64 + tx * 4;
#pragma unroll
    for (int ii = 0; ii < 4; ++ii) {
        float4 v;
        v.x = acc[ii][0]; v.y = acc[ii][1]; v.z = acc[ii][2]; v.w = acc[ii][3];
        *(float4*)(out + (r0 + ii) * DS + c0) = v;
    }
}

extern "C" void kernel_launch(void* const* d_in, const int* in_sizes, int n_in,
                              void* d_out, int out_size, void* d_ws, size_t ws_size,
                              hipStream_t stream)
{
    const float* s      = (const float*)d_in[0];
    const float* z      = (const float*)d_in[1];
    const float* mask   = (const float*)d_in[2];
    const float* q_w    = (const float*)d_in[3];
    const float* q_b    = (const float*)d_in[4];
    const float* k_w    = (const float*)d_in[5];
    const float* v_w    = (const float*)d_in[6];
    const float* g_w    = (const float*)d_in[7];
    const float* o_w    = (const float*)d_in[8];
    const float* z_ln_w = (const float*)d_in[9];
    const float* z_ln_b = (const float*)d_in[10];
    const float* z_w    = (const float*)d_in[11];

    float* Q  = (float*)d_ws;
    float* K  = Q + S * DS;
    float* VT = K + S * DS;
    float* G  = VT + S * DS;
    float* og = G + S * DS;
    float* scores = og + S * DS;            // H*S*S floats = 16.8 MB

    hipLaunchKernelGGL(proj_kernel, dim3(192), dim3(256), 0, stream,
                       s, q_w, q_b, k_w, v_w, g_w, Q, K, VT, G);
    hipLaunchKernelGGL(score_kernel, dim3(4096), dim3(256), 0, stream,
                       z, mask, z_ln_w, z_ln_b, z_w, Q, K, scores);
    hipLaunchKernelGGL(spv_kernel, dim3(S), dim3(256), 0, stream,
                       scores, VT, G, og);
    hipLaunchKernelGGL(out_kernel, dim3(48), dim3(256), 0, stream,
                       og, o_w, (float*)d_out);
}